// Round 2
// baseline (658.378 us; speedup 1.0000x reference)
//
#include <hip/hip_runtime.h>
#include <hip/hip_bf16.h>

#define EE 256
#define HIDD 150
#define HP 160
#define NN 384
#define NB 2
#define JTILE 64
#define NJT 6

typedef float f32x4 __attribute__((ext_vector_type(4)));
typedef _Float16 half8 __attribute__((ext_vector_type(8)));

// ---- pack W1c (rows 512..767 of W1) and W2 (+b2 in k-row 150) into MFMA B-frag order, fp16 ----
// frag k-convention (A and B): col=lane&15, k=(lane>>4)*8+e  (within each 32-K step)
__global__ void pack_weights(const float* __restrict__ W1, const float* __restrict__ W2,
                             const float* __restrict__ b2,
                             _Float16* __restrict__ w1p, _Float16* __restrict__ w2p) {
  int idx = blockIdx.x * blockDim.x + threadIdx.x;
  if (idx < 40960) {
    int e = idx & 7, lane = (idx >> 3) & 63, tile = idx >> 9;
    int t = tile % 10, k8 = tile / 10;
    int eg = k8 * 32 + ((lane >> 4) << 3) + e;
    int h = t * 16 + (lane & 15);
    w1p[idx] = (_Float16)((h < HIDD) ? W1[(512 + eg) * HIDD + h] : 0.f);
  }
  int idx2 = idx - 40960;
  if (idx2 >= 0 && idx2 < 25600) {
    int e = idx2 & 7, lane = (idx2 >> 3) & 63, tile = idx2 >> 9;
    int t = tile % 10, k5 = tile / 10;
    int kk = k5 * 32 + ((lane >> 4) << 3) + e;
    int h = t * 16 + (lane & 15);
    float v = 0.f;
    if (h < HIDD) {
      if (kk < HIDD) v = W2[kk * HIDD + h];
      else if (kk == HIDD) v = b2[h];   // b2 folded: h1[.][150] forced to 1.0 in main
    }
    w2p[idx2] = (_Float16)v;
  }
}

// ---- U[bn,h] = x@W1a + b1 (f32) ; Vt[h,bn] = x@W1b (f32, transposed) ; Xh = fp16(X) ----
__global__ void compute_uv(const float* __restrict__ X, const float* __restrict__ W1,
                           const float* __restrict__ b1,
                           _Float16* __restrict__ Xh, float* __restrict__ U,
                           float* __restrict__ Vt) {
  int bi = blockIdx.x;
  int tid = threadIdx.x;
  __shared__ float xs[EE];
  xs[tid] = X[bi * EE + tid];
  __syncthreads();
  Xh[bi * EE + tid] = (_Float16)xs[tid];
  if (tid < HIDD) {
    float u = 0.f, v = 0.f;
    for (int e = 0; e < EE; e++) {
      u = fmaf(xs[e], W1[e * HIDD + tid], u);
      v = fmaf(xs[e], W1[(EE + e) * HIDD + tid], v);
    }
    U[bi * HP + tid] = u + b1[tid];
    Vt[tid * (NB * NN) + bi] = v;
  } else if (tid < HP) {
    U[bi * HP + tid] = 0.f;
    Vt[tid * (NB * NN) + bi] = 0.f;
  }
}

// ---- main: one block per (b, i-pair, j-tile of 64); 4 waves, wave w owns j rows [w*16, w*16+16) ----
__global__ __launch_bounds__(256) void pair_main(
    const _Float16* __restrict__ Xh, const float* __restrict__ M,
    const float* __restrict__ W3, const float* __restrict__ b3,
    const float* __restrict__ U, const float* __restrict__ Vt,
    const _Float16* __restrict__ w1p, const _Float16* __restrict__ w2p,
    float* __restrict__ out) {
  int bx = blockIdx.x;
  int jt = bx % NJT;
  int ig = (bx / NJT) % (NN / 2);
  int b = bx / (NJT * (NN / 2));
  int i0 = ig * 2;

  int tid = threadIdx.x;
  int lane = tid & 63;
  int w = tid >> 6;
  int hcol = lane & 15;
  int rgrp = lane >> 4;

  __shared__ _Float16 xs[2][EE];
  __shared__ float Uf[2][HP];
  __shared__ float W3s[HP];
  __shared__ float ms[JTILE];
  __shared__ _Float16 h1s[4][16 * 192];  // per-wave 16 rows x 384B stride (swizzle-safe)

  // stage both i-rows of Xh (512 halfs = 256 dwords)
  {
    const unsigned* xr = reinterpret_cast<const unsigned*>(Xh + (b * NN + i0) * EE);
    reinterpret_cast<unsigned*>(&xs[0][0])[tid] = xr[tid];
  }
  for (int q = tid; q < 2 * HP; q += 256)
    (&Uf[0][0])[q] = U[(b * NN + i0) * HP + q];
  if (tid < HP) W3s[tid] = (tid < HIDD) ? W3[tid] : 0.f;
  if (tid < JTILE) ms[tid] = M[b * NN + jt * JTILE + tid];
  __syncthreads();

  // register-cache this lane's xj k-slices (fp16), reused for both i
  int jA = jt * JTILE + w * 16 + hcol;
  const half8* xjp = reinterpret_cast<const half8*>(Xh + (b * NN + jA) * EE + rgrp * 8);
  half8 xj[8];
  #pragma unroll
  for (int k8 = 0; k8 < 8; k8++) xj[k8] = xjp[k8 * 4];

  int jO0v = b * NN + jt * JTILE + w * 16 + rgrp * 4;  // Vt column base (4 consecutive j)
  char* hb = reinterpret_cast<char*>(&h1s[w][0]);

  for (int ii = 0; ii < 2; ii++) {
    // GEMM1 accumulators, init with U[i,h] + V[j,h] (Vt float4 over 4 j-rows)
    f32x4 acc[10];
    #pragma unroll
    for (int t = 0; t < 10; t++) {
      int h = t * 16 + hcol;
      float uf = Uf[ii][h];
      float4 vv = *reinterpret_cast<const float4*>(Vt + h * (NB * NN) + jO0v);
      acc[t][0] = uf + vv.x; acc[t][1] = uf + vv.y;
      acc[t][2] = uf + vv.z; acc[t][3] = uf + vv.w;
    }

    // GEMM1: C1[j,h] += sum_e (x_j[e]*x_i[e]) * W1c[e,h]   (A = pk_mul of fp16 slices)
    const half8* xip = reinterpret_cast<const half8*>(&xs[ii][rgrp * 8]);
    #pragma unroll
    for (int k8 = 0; k8 < 8; k8++) {
      half8 a = xip[k8 * 4] * xj[k8];
      const _Float16* wp = w1p + k8 * 5120 + lane * 8;
      #pragma unroll
      for (int t = 0; t < 10; t++) {
        half8 bfg = *reinterpret_cast<const half8*>(wp + t * 512);
        acc[t] = __builtin_amdgcn_mfma_f32_16x16x32_f16(a, bfg, acc[t], 0, 0, 0);
      }
    }

    // relu -> fp16 -> wave-private LDS (XOR swizzle bits 4..6, bijective at 384B stride)
    #pragma unroll
    for (int r = 0; r < 4; r++) {
      int jl = rgrp * 4 + r;
      int bb = jl * 384 + hcol * 2;
      int sz = (jl & 7) << 4;
      #pragma unroll
      for (int t = 0; t < 10; t++)
        *reinterpret_cast<_Float16*>(hb + ((bb + t * 32) ^ sz)) =
            (_Float16)fmaxf(acc[t][r], 0.f);
    }
    if (rgrp == 0)  // h1[j][150] = 1.0 so W2's k-row 150 (=b2) adds the bias
      *reinterpret_cast<_Float16*>(hb + ((hcol * 384 + 300) ^ ((hcol & 7) << 4))) =
          (_Float16)1.0f;

    // GEMM2 (b2 comes via k-row 150)
    #pragma unroll
    for (int t = 0; t < 10; t++) {
      acc[t][0] = 0.f; acc[t][1] = 0.f; acc[t][2] = 0.f; acc[t][3] = 0.f;
    }
    #pragma unroll
    for (int k5 = 0; k5 < 5; k5++) {
      int bo = (hcol * 384 + k5 * 64 + rgrp * 16) ^ ((hcol & 7) << 4);
      half8 a2 = *reinterpret_cast<const half8*>(hb + bo);
      const _Float16* wp = w2p + k5 * 5120 + lane * 8;
      #pragma unroll
      for (int t = 0; t < 10; t++) {
        half8 bfg = *reinterpret_cast<const half8*>(wp + t * 512);
        acc[t] = __builtin_amdgcn_mfma_f32_16x16x32_f16(a2, bfg, acc[t], 0, 0, 0);
      }
    }

    // layer 3: s[j] = sum_h relu(h2)[j,h] * W3[h]
    float pr0 = 0.f, pr1 = 0.f, pr2 = 0.f, pr3 = 0.f;
    #pragma unroll
    for (int t = 0; t < 10; t++) {
      float w3 = W3s[t * 16 + hcol];
      pr0 = fmaf(fmaxf(acc[t][0], 0.f), w3, pr0);
      pr1 = fmaf(fmaxf(acc[t][1], 0.f), w3, pr1);
      pr2 = fmaf(fmaxf(acc[t][2], 0.f), w3, pr2);
      pr3 = fmaf(fmaxf(acc[t][3], 0.f), w3, pr3);
    }
    #pragma unroll
    for (int mk = 1; mk <= 8; mk <<= 1) {
      pr0 += __shfl_xor(pr0, mk);
      pr1 += __shfl_xor(pr1, mk);
      pr2 += __shfl_xor(pr2, mk);
      pr3 += __shfl_xor(pr3, mk);
    }

    if (hcol == 0) {
      float mi = M[b * NN + i0 + ii];
      float bb3 = b3[0];
      int jl0 = w * 16 + rgrp * 4;
      float4 o;
      o.x = (mi + ms[jl0 + 0] + pr0 + bb3) * (1.f / 3.f);
      o.y = (mi + ms[jl0 + 1] + pr1 + bb3) * (1.f / 3.f);
      o.z = (mi + ms[jl0 + 2] + pr2 + bb3) * (1.f / 3.f);
      o.w = (mi + ms[jl0 + 3] + pr3 + bb3) * (1.f / 3.f);
      *reinterpret_cast<float4*>(out + (b * NN + i0 + ii) * NN + jt * JTILE + jl0) = o;
    }
  }
}

extern "C" void kernel_launch(void* const* d_in, const int* in_sizes, int n_in,
                              void* d_out, int out_size, void* d_ws, size_t ws_size,
                              hipStream_t stream) {
  const float* X  = (const float*)d_in[0];
  const float* M  = (const float*)d_in[1];
  const float* W1 = (const float*)d_in[2];
  const float* b1 = (const float*)d_in[3];
  const float* W2 = (const float*)d_in[4];
  const float* b2 = (const float*)d_in[5];
  const float* W3 = (const float*)d_in[6];
  const float* b3 = (const float*)d_in[7];
  float* out = (float*)d_out;

  float* U  = (float*)d_ws;                    // 768*160 f32
  float* Vt = U + NB * NN * HP;                // 160*768 f32
  _Float16* Xh  = (_Float16*)(Vt + HP * NB * NN); // 768*256 f16
  _Float16* w1p = Xh + NB * NN * EE;           // 40960 f16
  _Float16* w2p = w1p + 40960;                 // 25600 f16

  hipLaunchKernelGGL(pack_weights, dim3(260), dim3(256), 0, stream, W1, W2, b2, w1p, w2p);
  hipLaunchKernelGGL(compute_uv, dim3(NB * NN), dim3(EE), 0, stream, X, W1, b1, Xh, U, Vt);
  hipLaunchKernelGGL(pair_main, dim3(NB * (NN / 2) * NJT), dim3(256), 0, stream,
                     Xh, M, W3, b3, U, Vt, w1p, w2p, out);
}

// Round 3
// 130.129 us; speedup vs baseline: 5.0594x; 5.0594x over previous
//
#include <hip/hip_runtime.h>
#include <hip/hip_bf16.h>

#define EE 256
#define HIDD 150
#define HP 160
#define NN 384
#define NB 2
#define JTILE 64
#define NJT 6

typedef float f32x4 __attribute__((ext_vector_type(4)));
typedef _Float16 half8 __attribute__((ext_vector_type(8)));

// ---- pack W1c (rows 512..767 of W1) and W2 (+b2 in k-row 150) into MFMA B-frag order, fp16 ----
// frag k-convention (A and B): col=lane&15, k=(lane>>4)*8+e  (within each 32-K step)
__global__ void pack_weights(const float* __restrict__ W1, const float* __restrict__ W2,
                             const float* __restrict__ b2,
                             _Float16* __restrict__ w1p, _Float16* __restrict__ w2p) {
  int idx = blockIdx.x * blockDim.x + threadIdx.x;
  if (idx < 40960) {
    int e = idx & 7, lane = (idx >> 3) & 63, tile = idx >> 9;
    int t = tile % 10, k8 = tile / 10;
    int eg = k8 * 32 + ((lane >> 4) << 3) + e;
    int h = t * 16 + (lane & 15);
    w1p[idx] = (_Float16)((h < HIDD) ? W1[(512 + eg) * HIDD + h] : 0.f);
  }
  int idx2 = idx - 40960;
  if (idx2 >= 0 && idx2 < 25600) {
    int e = idx2 & 7, lane = (idx2 >> 3) & 63, tile = idx2 >> 9;
    int t = tile % 10, k5 = tile / 10;
    int kk = k5 * 32 + ((lane >> 4) << 3) + e;
    int h = t * 16 + (lane & 15);
    float v = 0.f;
    if (h < HIDD) {
      if (kk < HIDD) v = W2[kk * HIDD + h];
      else if (kk == HIDD) v = b2[h];   // b2 folded: h1[.][150] forced to 1.0 in main
    }
    w2p[idx2] = (_Float16)v;
  }
}

// ---- U[bn,h] = x@W1a + b1 (f32) ; Vt[h,bn] = x@W1b (f32, transposed) ; Xh = fp16(X) ----
__global__ void compute_uv(const float* __restrict__ X, const float* __restrict__ W1,
                           const float* __restrict__ b1,
                           _Float16* __restrict__ Xh, float* __restrict__ U,
                           float* __restrict__ Vt) {
  int bi = blockIdx.x;
  int tid = threadIdx.x;
  __shared__ float xs[EE];
  xs[tid] = X[bi * EE + tid];
  __syncthreads();
  Xh[bi * EE + tid] = (_Float16)xs[tid];
  if (tid < HIDD) {
    float u = 0.f, v = 0.f;
    for (int e = 0; e < EE; e++) {
      u = fmaf(xs[e], W1[e * HIDD + tid], u);
      v = fmaf(xs[e], W1[(EE + e) * HIDD + tid], v);
    }
    U[bi * HP + tid] = u + b1[tid];
    Vt[tid * (NB * NN) + bi] = v;
  } else if (tid < HP) {
    U[bi * HP + tid] = 0.f;
    Vt[tid * (NB * NN) + bi] = 0.f;
  }
}

// ---- main: one block per (b, i, j-tile of 64); 4 waves, wave w owns j rows [w*16, w*16+16) ----
// Explicit double-buffered B-fragment prefetch keeps ~10 L2 loads in flight.
__global__ __launch_bounds__(256, 2) void pair_main(
    const _Float16* __restrict__ Xh, const float* __restrict__ M,
    const float* __restrict__ W3, const float* __restrict__ b3,
    const float* __restrict__ U, const float* __restrict__ Vt,
    const _Float16* __restrict__ w1p, const _Float16* __restrict__ w2p,
    float* __restrict__ out) {
  int bx = blockIdx.x;
  int jt = bx % NJT;
  int i = (bx / NJT) % NN;
  int b = bx / (NJT * NN);

  int tid = threadIdx.x;
  int lane = tid & 63;
  int w = tid >> 6;
  int hcol = lane & 15;
  int rgrp = lane >> 4;

  __shared__ _Float16 xs[EE];
  __shared__ float Uf[HP];
  __shared__ float W3s[HP];
  __shared__ float ms[JTILE];
  __shared__ _Float16 h1s[4][16 * 192];  // per-wave 16 rows x 384B stride (swizzle-safe)

  const _Float16* xi = Xh + (b * NN + i) * EE;
  if (tid < 128)
    reinterpret_cast<unsigned*>(xs)[tid] = reinterpret_cast<const unsigned*>(xi)[tid];
  if (tid < HP) {
    Uf[tid] = U[(b * NN + i) * HP + tid];
    W3s[tid] = (tid < HIDD) ? W3[tid] : 0.f;
  }
  if (tid < JTILE) ms[tid] = M[b * NN + jt * JTILE + tid];
  __syncthreads();

  int jA = jt * JTILE + w * 16 + hcol;       // row of X this lane loads for A-frags
  int jO0v = b * NN + jt * JTILE + w * 16 + rgrp * 4;  // Vt column base (4 consecutive j)
  const half8* xjp = reinterpret_cast<const half8*>(Xh + (b * NN + jA) * EE + rgrp * 8);
  const half8* xip = reinterpret_cast<const half8*>(&xs[rgrp * 8]);
  const _Float16* wpb = w1p + lane * 8;

  // GEMM1 accumulators, init with U[i,h] + V[j,h] (Vt float4 over 4 j-rows)
  f32x4 acc[10];
  #pragma unroll
  for (int t = 0; t < 10; t++) {
    int h = t * 16 + hcol;
    float uf = Uf[h];
    float4 vv = *reinterpret_cast<const float4*>(Vt + h * (NB * NN) + jO0v);
    acc[t][0] = uf + vv.x; acc[t][1] = uf + vv.y;
    acc[t][2] = uf + vv.z; acc[t][3] = uf + vv.w;
  }

  // GEMM1: C1[j,h] += sum_e (x_j[e]*x_i[e]) * W1c[e,h]
  half8 bcur[10], bnxt[10];
  #pragma unroll
  for (int t = 0; t < 10; t++)
    bcur[t] = *reinterpret_cast<const half8*>(wpb + t * 512);
  #pragma unroll
  for (int k8 = 0; k8 < 8; k8++) {
    if (k8 < 7) {
      #pragma unroll
      for (int t = 0; t < 10; t++)
        bnxt[t] = *reinterpret_cast<const half8*>(wpb + (k8 + 1) * 5120 + t * 512);
    }
    half8 a = xip[k8 * 4] * xjp[k8 * 4];
    #pragma unroll
    for (int t = 0; t < 10; t++)
      acc[t] = __builtin_amdgcn_mfma_f32_16x16x32_f16(a, bcur[t], acc[t], 0, 0, 0);
    if (k8 < 7) {
      #pragma unroll
      for (int t = 0; t < 10; t++) bcur[t] = bnxt[t];
    }
  }

  // relu -> fp16 -> wave-private LDS (XOR swizzle bits 4..6, bijective at 384B stride)
  char* hb = reinterpret_cast<char*>(&h1s[w][0]);
  #pragma unroll
  for (int r = 0; r < 4; r++) {
    int jl = rgrp * 4 + r;
    int bb = jl * 384 + hcol * 2;
    int sz = (jl & 7) << 4;
    #pragma unroll
    for (int t = 0; t < 10; t++)
      *reinterpret_cast<_Float16*>(hb + ((bb + t * 32) ^ sz)) =
          (_Float16)fmaxf(acc[t][r], 0.f);
  }
  if (rgrp == 0)  // h1[j][150] = 1.0 so W2's k-row 150 (=b2) adds the bias
    *reinterpret_cast<_Float16*>(hb + ((hcol * 384 + 300) ^ ((hcol & 7) << 4))) =
        (_Float16)1.0f;

  // GEMM2 (b2 comes via k-row 150), same prefetch scheme
  #pragma unroll
  for (int t = 0; t < 10; t++) {
    acc[t][0] = 0.f; acc[t][1] = 0.f; acc[t][2] = 0.f; acc[t][3] = 0.f;
  }
  const _Float16* wpb2 = w2p + lane * 8;
  #pragma unroll
  for (int t = 0; t < 10; t++)
    bcur[t] = *reinterpret_cast<const half8*>(wpb2 + t * 512);
  #pragma unroll
  for (int k5 = 0; k5 < 5; k5++) {
    if (k5 < 4) {
      #pragma unroll
      for (int t = 0; t < 10; t++)
        bnxt[t] = *reinterpret_cast<const half8*>(wpb2 + (k5 + 1) * 5120 + t * 512);
    }
    int bo = (hcol * 384 + k5 * 64 + rgrp * 16) ^ ((hcol & 7) << 4);
    half8 a2 = *reinterpret_cast<const half8*>(hb + bo);
    #pragma unroll
    for (int t = 0; t < 10; t++)
      acc[t] = __builtin_amdgcn_mfma_f32_16x16x32_f16(a2, bcur[t], acc[t], 0, 0, 0);
    if (k5 < 4) {
      #pragma unroll
      for (int t = 0; t < 10; t++) bcur[t] = bnxt[t];
    }
  }

  // layer 3: s[j] = sum_h relu(h2)[j,h] * W3[h]
  float pr0 = 0.f, pr1 = 0.f, pr2 = 0.f, pr3 = 0.f;
  #pragma unroll
  for (int t = 0; t < 10; t++) {
    float w3 = W3s[t * 16 + hcol];
    pr0 = fmaf(fmaxf(acc[t][0], 0.f), w3, pr0);
    pr1 = fmaf(fmaxf(acc[t][1], 0.f), w3, pr1);
    pr2 = fmaf(fmaxf(acc[t][2], 0.f), w3, pr2);
    pr3 = fmaf(fmaxf(acc[t][3], 0.f), w3, pr3);
  }
  #pragma unroll
  for (int mk = 1; mk <= 8; mk <<= 1) {
    pr0 += __shfl_xor(pr0, mk);
    pr1 += __shfl_xor(pr1, mk);
    pr2 += __shfl_xor(pr2, mk);
    pr3 += __shfl_xor(pr3, mk);
  }

  if (hcol == 0) {
    float mi = M[b * NN + i];
    float bb3 = b3[0];
    int jl0 = w * 16 + rgrp * 4;
    float4 o;
    o.x = (mi + ms[jl0 + 0] + pr0 + bb3) * (1.f / 3.f);
    o.y = (mi + ms[jl0 + 1] + pr1 + bb3) * (1.f / 3.f);
    o.z = (mi + ms[jl0 + 2] + pr2 + bb3) * (1.f / 3.f);
    o.w = (mi + ms[jl0 + 3] + pr3 + bb3) * (1.f / 3.f);
    *reinterpret_cast<float4*>(out + (b * NN + i) * NN + jt * JTILE + jl0) = o;
  }
}

extern "C" void kernel_launch(void* const* d_in, const int* in_sizes, int n_in,
                              void* d_out, int out_size, void* d_ws, size_t ws_size,
                              hipStream_t stream) {
  const float* X  = (const float*)d_in[0];
  const float* M  = (const float*)d_in[1];
  const float* W1 = (const float*)d_in[2];
  const float* b1 = (const float*)d_in[3];
  const float* W2 = (const float*)d_in[4];
  const float* b2 = (const float*)d_in[5];
  const float* W3 = (const float*)d_in[6];
  const float* b3 = (const float*)d_in[7];
  float* out = (float*)d_out;

  float* U  = (float*)d_ws;                       // 768*160 f32
  float* Vt = U + NB * NN * HP;                   // 160*768 f32
  _Float16* Xh  = (_Float16*)(Vt + HP * NB * NN); // 768*256 f16
  _Float16* w1p = Xh + NB * NN * EE;              // 40960 f16
  _Float16* w2p = w1p + 40960;                    // 25600 f16

  hipLaunchKernelGGL(pack_weights, dim3(260), dim3(256), 0, stream, W1, W2, b2, w1p, w2p);
  hipLaunchKernelGGL(compute_uv, dim3(NB * NN), dim3(EE), 0, stream, X, W1, b1, Xh, U, Vt);
  hipLaunchKernelGGL(pair_main, dim3(NB * NN * NJT), dim3(256), 0, stream,
                     Xh, M, W3, b3, U, Vt, w1p, w2p, out);
}

// Round 4
// 112.895 us; speedup vs baseline: 5.8318x; 1.1526x over previous
//
#include <hip/hip_runtime.h>
#include <hip/hip_bf16.h>

#define EE 256
#define HIDD 150
#define HP 160
#define NN 384
#define NB 2
#define JTILE 64
#define NJT 6
#define RPB 8

typedef float f32x4 __attribute__((ext_vector_type(4)));
typedef _Float16 half8 __attribute__((ext_vector_type(8)));
typedef _Float16 half4 __attribute__((ext_vector_type(4)));

// ---- pack W1c (rows 512..767 of W1) and W2 (+b2 in k-row 150) into MFMA B-frag order, fp16 ----
// frag k-convention (A and B): col=lane&15, k=(lane>>4)*8+e  (within each 32-K step)
__global__ void pack_weights(const float* __restrict__ W1, const float* __restrict__ W2,
                             const float* __restrict__ b2,
                             _Float16* __restrict__ w1p, _Float16* __restrict__ w2p) {
  int idx = blockIdx.x * blockDim.x + threadIdx.x;
  if (idx < 40960) {
    int e = idx & 7, lane = (idx >> 3) & 63, tile = idx >> 9;
    int t = tile % 10, k8 = tile / 10;
    int eg = k8 * 32 + ((lane >> 4) << 3) + e;
    int h = t * 16 + (lane & 15);
    w1p[idx] = (_Float16)((h < HIDD) ? W1[(512 + eg) * HIDD + h] : 0.f);
  }
  int idx2 = idx - 40960;
  if (idx2 >= 0 && idx2 < 25600) {
    int e = idx2 & 7, lane = (idx2 >> 3) & 63, tile = idx2 >> 9;
    int t = tile % 10, k5 = tile / 10;
    int kk = k5 * 32 + ((lane >> 4) << 3) + e;
    int h = t * 16 + (lane & 15);
    float v = 0.f;
    if (h < HIDD) {
      if (kk < HIDD) v = W2[kk * HIDD + h];
      else if (kk == HIDD) v = b2[h];   // b2 folded: h1[.][150] forced to 1.0 in main
    }
    w2p[idx2] = (_Float16)v;
  }
}

// ---- U[bn,h] = x@W1a + b1 (f32) ; Vh[h,bn] = x@W1b (f16, transposed) ; Xh = fp16(X) ----
// 8 rows per block so W1 is streamed 96x total instead of 768x.
__global__ void compute_uv(const float* __restrict__ X, const float* __restrict__ W1,
                           const float* __restrict__ b1,
                           _Float16* __restrict__ Xh, float* __restrict__ U,
                           _Float16* __restrict__ Vh) {
  int r0 = blockIdx.x * RPB;
  int tid = threadIdx.x;
  __shared__ float xs[RPB][EE];
  for (int q = tid; q < RPB * EE; q += 256) {
    float xv = X[r0 * EE + q];
    xs[q >> 8][q & 255] = xv;
    Xh[r0 * EE + q] = (_Float16)xv;
  }
  __syncthreads();
  int h = tid;
  if (h < HP) {
    float u[RPB] = {0,0,0,0,0,0,0,0}, v[RPB] = {0,0,0,0,0,0,0,0};
    if (h < HIDD) {
      for (int e = 0; e < EE; e++) {
        float wa = W1[e * HIDD + h];
        float wb = W1[(EE + e) * HIDD + h];
        #pragma unroll
        for (int r = 0; r < RPB; r++) {
          u[r] = fmaf(xs[r][e], wa, u[r]);
          v[r] = fmaf(xs[r][e], wb, v[r]);
        }
      }
      float bb = b1[h];
      #pragma unroll
      for (int r = 0; r < RPB; r++) u[r] += bb;
    }
    #pragma unroll
    for (int r = 0; r < RPB; r++) {
      U[(r0 + r) * HP + h] = u[r];
      Vh[h * (NB * NN) + r0 + r] = (_Float16)v[r];
    }
  }
}

// ---- main: block = (b, i-pair, j-tile of 64); 2 waves, wave w owns i = i0+w, ALL 64 j via 4 A-frags ----
// Each B-fragment load feeds 4 MFMAs -> weight L2 traffic /4 vs round 3.
__global__ __launch_bounds__(128, 2) void pair_main(
    const _Float16* __restrict__ Xh, const float* __restrict__ M,
    const float* __restrict__ W3, const float* __restrict__ b3,
    const float* __restrict__ U, const _Float16* __restrict__ Vh,
    const _Float16* __restrict__ w1p, const _Float16* __restrict__ w2p,
    float* __restrict__ out) {
  int bx = blockIdx.x;
  int jt = bx % NJT;
  int ig = (bx / NJT) % (NN / 2);
  int b = bx / (NJT * (NN / 2));
  int i0 = ig * 2;

  int tid = threadIdx.x;
  int lane = tid & 63;
  int w = tid >> 6;
  int hcol = lane & 15;
  int rgrp = lane >> 4;
  int i = i0 + w;

  __shared__ _Float16 xs[2][EE];
  __shared__ float Uf[2][HP];
  __shared__ float W3s[HP];
  __shared__ float ms[JTILE];
  __shared__ _Float16 h1s[2][64 * 192];  // per-wave 64 rows x 384B stride (swizzle-safe)

  for (int q = tid; q < 256; q += 128)
    reinterpret_cast<unsigned*>(&xs[0][0])[q] =
        reinterpret_cast<const unsigned*>(Xh + (b * NN + i0) * EE)[q];
  for (int q = tid; q < 2 * HP; q += 128)
    (&Uf[0][0])[q] = U[(b * NN + i0) * HP + q];
  for (int q = tid; q < HP; q += 128) W3s[q] = (q < HIDD) ? W3[q] : 0.f;
  if (tid < JTILE) ms[tid] = M[b * NN + jt * JTILE + tid];
  __syncthreads();

  // per-lane xj row pointers for the 4 A-fragments (rows jt*64 + af*16 + hcol)
  const _Float16* xrb = Xh + (b * NN + jt * JTILE + hcol) * EE + rgrp * 8;
  const half8* xr0 = reinterpret_cast<const half8*>(xrb);
  const half8* xr1 = reinterpret_cast<const half8*>(xrb + 16 * EE);
  const half8* xr2 = reinterpret_cast<const half8*>(xrb + 32 * EE);
  const half8* xr3 = reinterpret_cast<const half8*>(xrb + 48 * EE);

  // GEMM1 accumulators [af][t], init with U[i,h] + V[j,h] (Vh half4 over 4 j-rows)
  f32x4 acc[4][10];
  #pragma unroll
  for (int t = 0; t < 10; t++) {
    int h = t * 16 + hcol;
    float uf = Uf[w][h];
    const _Float16* vb = Vh + h * (NB * NN) + b * NN + jt * JTILE + rgrp * 4;
    #pragma unroll
    for (int af = 0; af < 4; af++) {
      half4 vv = *reinterpret_cast<const half4*>(vb + af * 16);
      acc[af][t][0] = uf + (float)vv[0];
      acc[af][t][1] = uf + (float)vv[1];
      acc[af][t][2] = uf + (float)vv[2];
      acc[af][t][3] = uf + (float)vv[3];
    }
  }

  // GEMM1: C1[j,h] += sum_e (x_j[e]*x_i[e]) * W1c[e,h]
  #pragma unroll
  for (int k8 = 0; k8 < 8; k8++) {
    half8 xi_s = *reinterpret_cast<const half8*>(&xs[w][k8 * 32 + rgrp * 8]);
    half8 a0 = xi_s * xr0[k8 * 4];
    half8 a1 = xi_s * xr1[k8 * 4];
    half8 a2 = xi_s * xr2[k8 * 4];
    half8 a3 = xi_s * xr3[k8 * 4];
    const _Float16* wp = w1p + k8 * 5120 + lane * 8;
    #pragma unroll
    for (int t = 0; t < 10; t++) {
      half8 bf = *reinterpret_cast<const half8*>(wp + t * 512);
      acc[0][t] = __builtin_amdgcn_mfma_f32_16x16x32_f16(a0, bf, acc[0][t], 0, 0, 0);
      acc[1][t] = __builtin_amdgcn_mfma_f32_16x16x32_f16(a1, bf, acc[1][t], 0, 0, 0);
      acc[2][t] = __builtin_amdgcn_mfma_f32_16x16x32_f16(a2, bf, acc[2][t], 0, 0, 0);
      acc[3][t] = __builtin_amdgcn_mfma_f32_16x16x32_f16(a3, bf, acc[3][t], 0, 0, 0);
    }
  }

  // relu -> fp16 -> wave-private LDS (XOR swizzle bits 4..6, bijective at 384B stride)
  char* hb = reinterpret_cast<char*>(&h1s[w][0]);
  #pragma unroll
  for (int af = 0; af < 4; af++) {
    #pragma unroll
    for (int r = 0; r < 4; r++) {
      int jl = af * 16 + rgrp * 4 + r;
      int bb = jl * 384 + hcol * 2;
      int sz = (jl & 7) << 4;
      #pragma unroll
      for (int t = 0; t < 10; t++)
        *reinterpret_cast<_Float16*>(hb + ((bb + t * 32) ^ sz)) =
            (_Float16)fmaxf(acc[af][t][r], 0.f);
    }
  }
  // h1[j][150] = 1.0 so W2's k-row 150 (=b2) adds the bias; one row per lane
  *reinterpret_cast<_Float16*>(hb + ((lane * 384 + 300) ^ ((lane & 7) << 4))) =
      (_Float16)1.0f;

  // GEMM2 (b2 comes via k-row 150)
  #pragma unroll
  for (int af = 0; af < 4; af++)
    #pragma unroll
    for (int t = 0; t < 10; t++) {
      acc[af][t][0] = 0.f; acc[af][t][1] = 0.f;
      acc[af][t][2] = 0.f; acc[af][t][3] = 0.f;
    }
  #pragma unroll
  for (int k5 = 0; k5 < 5; k5++) {
    half8 a0 = *reinterpret_cast<const half8*>(
        hb + (((0 * 16 + hcol) * 384 + k5 * 64 + rgrp * 16) ^ ((hcol & 7) << 4)));
    half8 a1 = *reinterpret_cast<const half8*>(
        hb + (((1 * 16 + hcol) * 384 + k5 * 64 + rgrp * 16) ^ ((hcol & 7) << 4)));
    half8 a2 = *reinterpret_cast<const half8*>(
        hb + (((2 * 16 + hcol) * 384 + k5 * 64 + rgrp * 16) ^ ((hcol & 7) << 4)));
    half8 a3 = *reinterpret_cast<const half8*>(
        hb + (((3 * 16 + hcol) * 384 + k5 * 64 + rgrp * 16) ^ ((hcol & 7) << 4)));
    const _Float16* wp = w2p + k5 * 5120 + lane * 8;
    #pragma unroll
    for (int t = 0; t < 10; t++) {
      half8 bf = *reinterpret_cast<const half8*>(wp + t * 512);
      acc[0][t] = __builtin_amdgcn_mfma_f32_16x16x32_f16(a0, bf, acc[0][t], 0, 0, 0);
      acc[1][t] = __builtin_amdgcn_mfma_f32_16x16x32_f16(a1, bf, acc[1][t], 0, 0, 0);
      acc[2][t] = __builtin_amdgcn_mfma_f32_16x16x32_f16(a2, bf, acc[2][t], 0, 0, 0);
      acc[3][t] = __builtin_amdgcn_mfma_f32_16x16x32_f16(a3, bf, acc[3][t], 0, 0, 0);
    }
  }

  // layer 3: s[j] = sum_h relu(h2)[j,h] * W3[h], 16-lane shuffle reduce
  float mi = M[b * NN + i];
  float bb3 = b3[0];
  #pragma unroll
  for (int af = 0; af < 4; af++) {
    float pr0 = 0.f, pr1 = 0.f, pr2 = 0.f, pr3 = 0.f;
    #pragma unroll
    for (int t = 0; t < 10; t++) {
      float w3 = W3s[t * 16 + hcol];
      pr0 = fmaf(fmaxf(acc[af][t][0], 0.f), w3, pr0);
      pr1 = fmaf(fmaxf(acc[af][t][1], 0.f), w3, pr1);
      pr2 = fmaf(fmaxf(acc[af][t][2], 0.f), w3, pr2);
      pr3 = fmaf(fmaxf(acc[af][t][3], 0.f), w3, pr3);
    }
    #pragma unroll
    for (int mk = 1; mk <= 8; mk <<= 1) {
      pr0 += __shfl_xor(pr0, mk);
      pr1 += __shfl_xor(pr1, mk);
      pr2 += __shfl_xor(pr2, mk);
      pr3 += __shfl_xor(pr3, mk);
    }
    if (hcol == 0) {
      int jl0 = af * 16 + rgrp * 4;
      float4 o;
      o.x = (mi + ms[jl0 + 0] + pr0 + bb3) * (1.f / 3.f);
      o.y = (mi + ms[jl0 + 1] + pr1 + bb3) * (1.f / 3.f);
      o.z = (mi + ms[jl0 + 2] + pr2 + bb3) * (1.f / 3.f);
      o.w = (mi + ms[jl0 + 3] + pr3 + bb3) * (1.f / 3.f);
      *reinterpret_cast<float4*>(out + (b * NN + i) * NN + jt * JTILE + jl0) = o;
    }
  }
}

extern "C" void kernel_launch(void* const* d_in, const int* in_sizes, int n_in,
                              void* d_out, int out_size, void* d_ws, size_t ws_size,
                              hipStream_t stream) {
  const float* X  = (const float*)d_in[0];
  const float* M  = (const float*)d_in[1];
  const float* W1 = (const float*)d_in[2];
  const float* b1 = (const float*)d_in[3];
  const float* W2 = (const float*)d_in[4];
  const float* b2 = (const float*)d_in[5];
  const float* W3 = (const float*)d_in[6];
  const float* b3 = (const float*)d_in[7];
  float* out = (float*)d_out;

  float* U  = (float*)d_ws;                        // 768*160 f32
  _Float16* Vh  = (_Float16*)(U + NB * NN * HP);   // 160*768 f16
  _Float16* Xh  = Vh + HP * NB * NN;               // 768*256 f16
  _Float16* w1p = Xh + NB * NN * EE;               // 40960 f16
  _Float16* w2p = w1p + 40960;                     // 25600 f16

  hipLaunchKernelGGL(pack_weights, dim3(260), dim3(256), 0, stream, W1, W2, b2, w1p, w2p);
  hipLaunchKernelGGL(compute_uv, dim3(NB * NN / RPB), dim3(256), 0, stream, X, W1, b1, Xh, U, Vh);
  hipLaunchKernelGGL(pair_main, dim3(NB * (NN / 2) * NJT), dim3(128), 0, stream,
                     Xh, M, W3, b3, U, Vh, w1p, w2p, out);
}